// Round 6
// baseline (263.325 us; speedup 1.0000x reference)
//
#include <hip/hip_runtime.h>
#include <math.h>

// labels = argmin_k ||c1_k||^2 - 2*x.c1_k, x = inpt[:,64:128] (131072x64),
// centers1 (1024x64). centers0 unused. Output int32 labels.
constexpr int N_ROWS   = 131072;
constexpr int INPT_DIM = 128;
constexpr int DIM      = 64;
constexpr int COL_OFF  = 64;
constexpr int NCENT    = 1024;

constexpr int TM    = 64;           // rows per block (shared by all 4 waves)
constexpr int NTILE = NCENT / 16;   // 64 tiles of 16 centers
constexpr int MAXC  = 16;           // candidates/row (E~1.5 under final thresh)
constexpr int NWAVE = 4;            // waves per block, center-split
constexpr int TPW   = NTILE / NWAVE; // 16 tiles per wave, REGISTER-STATIONARY

typedef short short8 __attribute__((ext_vector_type(8)));
typedef float f32x4  __attribute__((ext_vector_type(4)));

// ws: [0,8192) f64 cnorm | [8192,12288) f32 cnorm | [12288,12292) maxC bits
//     [16384, 16384+131072) bf16 centers, MFMA-fragment-linear:
//     frag (tile t, khalf f) lane l: 8 bf16 at ((t*2+f)*64 + l)*8
//     = centers[t*16 + (l&15)][f*32 + (l>>4)*8 + j]   (B[n][k], m89 layout)

__device__ __forceinline__ unsigned short f2bf(float f) {
    unsigned u = __float_as_uint(f);
    u += 0x7fff + ((u >> 16) & 1);          // round-to-nearest-even
    return (unsigned short)(u >> 16);
}

__device__ __forceinline__ double exact_score(const float* __restrict__ c,
                                              const float* __restrict__ x, double cn) {
    double acc = 0.0;
#pragma unroll
    for (int d = 0; d < DIM; ++d)
        acc = fma((double)c[d], (double)x[d], acc);
    return fma(-2.0, acc, cn);
}

// ---------------------------------------------------------------------------
// Prep v3: 4 threads per center (4096 threads), 64 blocks x 64 so 64 CUs
// participate. Each thread reads a contiguous 64B quarter-row (coalesced),
// shuffle-combines the norm over the 4 lanes, writes its 2 fragment-quads.
// ---------------------------------------------------------------------------
__global__ __launch_bounds__(64) void prep_kernel(const float* __restrict__ centers,
                                                  double* __restrict__ cnorm_d,
                                                  float* __restrict__ cnorm_f,
                                                  int* __restrict__ maxc_i,
                                                  unsigned short* __restrict__ cbf) {
    int tid = blockIdx.x * 64 + threadIdx.x;    // 0..4095
    int k = tid >> 2, kq = tid & 3;             // center, quarter
    const float* c = centers + (size_t)k * DIM + kq * 16;
    float cf[16];
    double sd = 0.0;
#pragma unroll
    for (int j = 0; j < 4; ++j) {
        float4 v = *reinterpret_cast<const float4*>(c + j * 4);
        cf[j * 4] = v.x; cf[j * 4 + 1] = v.y; cf[j * 4 + 2] = v.z; cf[j * 4 + 3] = v.w;
        sd = fma((double)v.x, (double)v.x, sd);
        sd = fma((double)v.y, (double)v.y, sd);
        sd = fma((double)v.z, (double)v.z, sd);
        sd = fma((double)v.w, (double)v.w, sd);
    }
    // the 4 lanes of one center are adjacent (tid = k*4+kq): xor-combine norm
    sd += __shfl_xor(sd, 1);
    sd += __shfl_xor(sd, 2);
    if (kq == 0) { cnorm_d[k] = sd; cnorm_f[k] = (float)sd; }

    // dims [kq*16, kq*16+16) -> khalf f = kq>>1, quads qq = (kq&1)*2 + h
    int t = k >> 4, n = k & 15, f = kq >> 1;
#pragma unroll
    for (int h = 0; h < 2; ++h) {
        int qq = (kq & 1) * 2 + h;
        const float* s = cf + h * 8;
        uint4 w;
        w.x = (unsigned)f2bf(s[0]) | ((unsigned)f2bf(s[1]) << 16);
        w.y = (unsigned)f2bf(s[2]) | ((unsigned)f2bf(s[3]) << 16);
        w.z = (unsigned)f2bf(s[4]) | ((unsigned)f2bf(s[5]) << 16);
        w.w = (unsigned)f2bf(s[6]) | ((unsigned)f2bf(s[7]) << 16);
        *reinterpret_cast<uint4*>(cbf + ((size_t)((t * 2 + f) * 64 + qq * 16 + n)) * 8) = w;
    }
    float nm = sqrtf((float)sd);
#pragma unroll
    for (int mk = 1; mk < 64; mk <<= 1)
        nm = fmaxf(nm, __shfl_xor(nm, mk));
    if (threadIdx.x == 0) atomicMax(maxc_i, __float_as_int(nm));  // poison<0 loses
}

// ---------------------------------------------------------------------------
// Main v6: B-STATIONARY center-split. R2-R4 post-mortem: 186us invariant to
// spills (657/127/0 MB) and occupancy (19.7/9.3%) -> bound by the per-block
// stall chain (16 loadGroups/wave with ~150cyc prefetch cover for ~300cyc L2
// latency, x2 passes, + barriers + wave0-only resolve), not by wave count.
// v6: each wave's 16 B-tiles = 512B/lane = 128 VGPR -> load ONCE into
// registers; both passes then run with ZERO loads in the hot loop (pure
// MFMA+VALU from regs). Pass-2 B reload eliminated (L2 B-traffic halves).
// Resolve spread over all 4 waves (16 rows each). MFMA-pipe floor at
// 2 waves/SIMD: ~40K cyc/CU ~= 16.5us. VGPR ~230 (launch_bounds(256,1),
// no clamp -> no spills per R4).
// (R5 was an infra failure -- container died twice before any measurement;
// source re-audited for races/OOB/pressure and resubmitted unchanged.)
// ---------------------------------------------------------------------------
__global__ __launch_bounds__(256, 1) void label_kernel(
        const float* __restrict__ inpt, const float* __restrict__ centers,
        const double* __restrict__ cnorm_d, const float* __restrict__ cnorm_f,
        const int* __restrict__ maxc_i, const unsigned short* __restrict__ cbf,
        int* __restrict__ out) {
    __shared__ unsigned short A_lds[TM][72];   // 144B rows: frag reads 2-way (free)
    __shared__ float cn_lds[NCENT];
    __shared__ float margin_lds[TM];
    __shared__ float pmin_lds[TM][NWAVE];      // per-wave partial row-min
    __shared__ int   cand[TM][MAXC];
    __shared__ int   ccount[TM];

    const int t    = threadIdx.x;              // 0..255
    const int lane = t & 63;
    const int wv   = t >> 6;                   // wave id 0..3
    const int rowBase = blockIdx.x * TM;

    // ---- stage: 4 threads per row, each a contiguous 64B quarter (coalesced)
    {
        const int row = t >> 2, qt = t & 3;
        const float* xp = inpt + (size_t)(rowBase + row) * INPT_DIM + COL_OFF + qt * 16;
        float nx2 = 0.f;
#pragma unroll
        for (int j = 0; j < 4; ++j) {
            float4 v = *reinterpret_cast<const float4*>(xp + j * 4);
            nx2 = fmaf(v.x, v.x, fmaf(v.y, v.y, fmaf(v.z, v.z, fmaf(v.w, v.w, nx2))));
            unsigned u0 = (unsigned)f2bf(v.x) | ((unsigned)f2bf(v.y) << 16);
            unsigned u1 = (unsigned)f2bf(v.z) | ((unsigned)f2bf(v.w) << 16);
            int col = qt * 16 + j * 4;
            *reinterpret_cast<unsigned*>(&A_lds[row][col])     = u0;
            *reinterpret_cast<unsigned*>(&A_lds[row][col + 2]) = u1;
        }
        // quarter-norm combine: lanes t^1, t^2 share the row (t = row*4+qt)
        nx2 += __shfl_xor(nx2, 1);
        nx2 += __shfl_xor(nx2, 2);
        // bf16 score err <= 2^-7|x||c| each way; formula unchanged since R3 (absmax=0)
        if (qt == 0)
            margin_lds[row] = (1.5f / 64.f) * sqrtf(nx2) * __int_as_float(maxc_i[0]) + 1e-3f;
        if (t < TM) ccount[t] = 0;
        *reinterpret_cast<float4*>(&cn_lds[t * 4]) =
            *reinterpret_cast<const float4*>(cnorm_f + t * 4);
    }

    // ---- B-panel load: this wave's 16 tiles, register-stationary (512B/lane)
    const short8* bfrag = reinterpret_cast<const short8*>(cbf);
    const int tbase = wv * TPW;
    short8 Bf0[TPW], Bf1[TPW];
#pragma unroll
    for (int tt = 0; tt < TPW; ++tt) {
        Bf0[tt] = bfrag[((tbase + tt) * 2 + 0) * 64 + lane];
        Bf1[tt] = bfrag[((tbase + tt) * 2 + 1) * 64 + lane];
    }

    __syncthreads();

    const int m = lane & 15, q = lane >> 4;
    short8 af0[4], af1[4];   // m89: A[m=lane&15][k=q*8+j]; 4 sets of 16 rows
#pragma unroll
    for (int s = 0; s < 4; ++s) {
        af0[s] = *reinterpret_cast<const short8*>(&A_lds[s * 16 + m][q * 8]);
        af1[s] = *reinterpret_cast<const short8*>(&A_lds[s * 16 + m][32 + q * 8]);
    }

    // ================= pass 1: running min only (zero loads, pure regs) ====
    float rmin[4][4];
#pragma unroll
    for (int s = 0; s < 4; ++s)
#pragma unroll
        for (int r4 = 0; r4 < 4; ++r4) rmin[s][r4] = INFINITY;

#pragma unroll
    for (int tt = 0; tt < TPW; ++tt) {
        float cn = cn_lds[(tbase + tt) * 16 + m];
#pragma unroll
        for (int s = 0; s < 4; ++s) {
            f32x4 acc = {0.f, 0.f, 0.f, 0.f};
            acc = __builtin_amdgcn_mfma_f32_16x16x32_bf16(af0[s], Bf0[tt], acc, 0, 0, 0);
            acc = __builtin_amdgcn_mfma_f32_16x16x32_bf16(af1[s], Bf1[tt], acc, 0, 0, 0);
#pragma unroll
            for (int r4 = 0; r4 < 4; ++r4)   // D: col=m (center), row=q*4+r4
                rmin[s][r4] = fminf(rmin[s][r4], fmaf(-2.f, acc[r4], cn));
        }
    }

    // ---- cross-lane (16-lane m-groups) then cross-wave partial-min combine
#pragma unroll
    for (int s = 0; s < 4; ++s) {
#pragma unroll
        for (int r4 = 0; r4 < 4; ++r4) {
            float v = rmin[s][r4];
            v = fminf(v, __shfl_xor(v, 1));
            v = fminf(v, __shfl_xor(v, 2));
            v = fminf(v, __shfl_xor(v, 4));
            v = fminf(v, __shfl_xor(v, 8));
            if (m == 0) pmin_lds[s * 16 + q * 4 + r4][wv] = v;
        }
    }
    __syncthreads();

    // ---- global per-row thresholds (identical across waves)
    float thresh[4][4], tmax[4];
#pragma unroll
    for (int s = 0; s < 4; ++s) {
        tmax[s] = -INFINITY;
#pragma unroll
        for (int r4 = 0; r4 < 4; ++r4) {
            int row = s * 16 + q * 4 + r4;
            float4 p = *reinterpret_cast<const float4*>(&pmin_lds[row][0]);
            float v = fminf(fminf(p.x, p.y), fminf(p.z, p.w)) + margin_lds[row];
            thresh[s][r4] = v;
            tmax[s] = fmaxf(tmax[s], v);
        }
    }

    // ================= pass 2: recompute + append candidates (regs only) ===
#pragma unroll
    for (int tt = 0; tt < TPW; ++tt) {
        float cn = cn_lds[(tbase + tt) * 16 + m];
#pragma unroll
        for (int s = 0; s < 4; ++s) {
            f32x4 acc = {0.f, 0.f, 0.f, 0.f};
            acc = __builtin_amdgcn_mfma_f32_16x16x32_bf16(af0[s], Bf0[tt], acc, 0, 0, 0);
            acc = __builtin_amdgcn_mfma_f32_16x16x32_bf16(af1[s], Bf1[tt], acc, 0, 0, 0);
            float sc[4];
#pragma unroll
            for (int r4 = 0; r4 < 4; ++r4)
                sc[r4] = fmaf(-2.f, acc[r4], cn);
            float smin = fminf(fminf(sc[0], sc[1]), fminf(sc[2], sc[3]));
            if (smin < tmax[s]) {
#pragma unroll
                for (int r4 = 0; r4 < 4; ++r4) {
                    if (sc[r4] < thresh[s][r4]) {   // pass1==pass2 scores (determinism)
                        int row = s * 16 + q * 4 + r4;
                        int slot = atomicAdd(&ccount[row], 1);
                        if (slot < MAXC) cand[row][slot] = (tbase + tt) * 16 + m;
                    }
                }
            }
        }
    }
    __syncthreads();

    // ---- exact f64 resolve, spread across ALL 4 waves: wave wv resolves
    //      rows [wv*16, wv*16+16) on lanes 0-15 (argmin with k-tie-break is
    //      candidate-order-independent -> deterministic output)
    if (lane < 16) {
        int row = wv * 16 + lane;
        int cnt = ccount[row];
        int best;
        if (cnt == 1) {
            best = cand[row][0];
        } else {
            const float* xp = inpt + (size_t)(rowBase + row) * INPT_DIM + COL_OFF;
            double bestv = 1e300;
            best = 0x7fffffff;
            if (cnt <= MAXC) {
                for (int j = 0; j < cnt; ++j) {
                    int k = cand[row][j];
                    double s = exact_score(centers + (size_t)k * DIM, xp, cnorm_d[k]);
                    if (s < bestv || (s == bestv && k < best)) { bestv = s; best = k; }
                }
            } else {  // overflow fallback: full exact scan (P ~ 0)
                for (int k = 0; k < NCENT; ++k) {
                    double s = exact_score(centers + (size_t)k * DIM, xp, cnorm_d[k]);
                    if (s < bestv) { bestv = s; best = k; }
                }
            }
        }
        out[rowBase + row] = best;
    }
}

// ---------------------------------------------------------------------------
extern "C" void kernel_launch(void* const* d_in, const int* in_sizes, int n_in,
                              void* d_out, int out_size, void* d_ws, size_t ws_size,
                              hipStream_t stream) {
    const float* inpt     = (const float*)d_in[0];
    const float* centers1 = (const float*)d_in[2];   // centers0 (d_in[1]) unused
    int* out = (int*)d_out;

    char* ws = (char*)d_ws;
    double* cnorm_d = (double*)ws;
    float*  cnorm_f = (float*)(ws + 8192);
    int*    maxc_i  = (int*)(ws + 12288);
    unsigned short* cbf = (unsigned short*)(ws + 16384);

    prep_kernel<<<64, 64, 0, stream>>>(centers1, cnorm_d, cnorm_f, maxc_i, cbf);
    label_kernel<<<N_ROWS / TM, 256, 0, stream>>>(inpt, centers1, cnorm_d, cnorm_f,
                                                  maxc_i, cbf, out);
}

// Round 7
// 164.324 us; speedup vs baseline: 1.6025x; 1.6025x over previous
//
#include <hip/hip_runtime.h>
#include <math.h>

// labels = argmin_k ||c1_k||^2 - 2*x.c1_k, x = inpt[:,64:128] (131072x64),
// centers1 (1024x64). centers0 unused. Output int32 labels.
constexpr int N_ROWS   = 131072;
constexpr int INPT_DIM = 128;
constexpr int DIM      = 64;
constexpr int COL_OFF  = 64;
constexpr int NCENT    = 1024;

constexpr int TM    = 32;           // rows per block (one wave, 2 A-frag sets)
constexpr int NTILE = NCENT / 16;   // 64 tiles of 16 centers
constexpr int MAXC  = 16;           // candidates/row (E~1.5 under final thresh)
constexpr int NS    = TM / 16;      // A-frag sets (2)

typedef short short8 __attribute__((ext_vector_type(8)));
typedef float f32x4  __attribute__((ext_vector_type(4)));

// ws: [0,8192) f64 cnorm | [8192,12288) f32 cnorm | [12288,12292) maxC bits
//     [16384, 16384+131072) bf16 centers, MFMA-fragment-linear:
//     frag (tile t, khalf f) lane l: 8 bf16 at ((t*2+f)*64 + l)*8
//     = centers[t*16 + (l&15)][f*32 + (l>>4)*8 + j]   (B[n][k], m89 layout)

__device__ __forceinline__ unsigned short f2bf(float f) {
    unsigned u = __float_as_uint(f);
    u += 0x7fff + ((u >> 16) & 1);          // round-to-nearest-even
    return (unsigned short)(u >> 16);
}

__device__ __forceinline__ double exact_score(const float* __restrict__ c,
                                              const float* __restrict__ x, double cn) {
    double acc = 0.0;
#pragma unroll
    for (int d = 0; d < DIM; ++d)
        acc = fma((double)c[d], (double)x[d], acc);
    return fma(-2.0, acc, cn);
}

// ---------------------------------------------------------------------------
// Prep (R0 version, proven): 4 threads per center (4096 threads, 16x256).
// Each thread reads a contiguous 64B quarter-row (coalesced), shuffle-
// combines the norm over the 4 lanes, writes its 2 fragment-quads.
// ---------------------------------------------------------------------------
__global__ __launch_bounds__(256) void prep_kernel(const float* __restrict__ centers,
                                                   double* __restrict__ cnorm_d,
                                                   float* __restrict__ cnorm_f,
                                                   int* __restrict__ maxc_i,
                                                   unsigned short* __restrict__ cbf) {
    int tid = blockIdx.x * 256 + threadIdx.x;   // 0..4095
    int k = tid >> 2, kq = tid & 3;             // center, quarter
    const float* c = centers + (size_t)k * DIM + kq * 16;
    float cf[16];
    double sd = 0.0;
#pragma unroll
    for (int j = 0; j < 4; ++j) {
        float4 v = *reinterpret_cast<const float4*>(c + j * 4);
        cf[j * 4] = v.x; cf[j * 4 + 1] = v.y; cf[j * 4 + 2] = v.z; cf[j * 4 + 3] = v.w;
        sd = fma((double)v.x, (double)v.x, sd);
        sd = fma((double)v.y, (double)v.y, sd);
        sd = fma((double)v.z, (double)v.z, sd);
        sd = fma((double)v.w, (double)v.w, sd);
    }
    // the 4 lanes of one center are adjacent (tid = k*4+kq): xor-combine norm
    sd += __shfl_xor(sd, 1);
    sd += __shfl_xor(sd, 2);
    if (kq == 0) { cnorm_d[k] = sd; cnorm_f[k] = (float)sd; }

    // dims [kq*16, kq*16+16) -> khalf f = kq>>1, quads qq = (kq&1)*2 + h
    int t = k >> 4, n = k & 15, f = kq >> 1;
#pragma unroll
    for (int h = 0; h < 2; ++h) {
        int qq = (kq & 1) * 2 + h;
        const float* s = cf + h * 8;
        uint4 w;
        w.x = (unsigned)f2bf(s[0]) | ((unsigned)f2bf(s[1]) << 16);
        w.y = (unsigned)f2bf(s[2]) | ((unsigned)f2bf(s[3]) << 16);
        w.z = (unsigned)f2bf(s[4]) | ((unsigned)f2bf(s[5]) << 16);
        w.w = (unsigned)f2bf(s[6]) | ((unsigned)f2bf(s[7]) << 16);
        *reinterpret_cast<uint4*>(cbf + ((size_t)((t * 2 + f) * 64 + qq * 16 + n)) * 8) = w;
    }
    float nm = sqrtf((float)sd);
#pragma unroll
    for (int mk = 1; mk < 64; mk <<= 1)
        nm = fmaxf(nm, __shfl_xor(nm, mk));
    if ((threadIdx.x & 63) == 0) atomicMax(maxc_i, __float_as_int(nm));  // poison<0 loses
}

// ---------------------------------------------------------------------------
// Main v7: REVERT to the proven R0 single-wave structure (80us label; every
// 4-wave barrier-locked variant R1-R6 pinned at 186us regardless of spills /
// occupancy / register-stationary B -- the wave team itself is the curse).
// One change vs R0: TM 64->32 (grid 2048->4096 one-wave blocks). R0's
// counters showed grid-limited residency (8 waves/CU cap, occ 19.6%, issue
// ~50% idle on the B-load stream); TM=32 doubles independent waves/CU to 16
// (VGPR ~70 and LDS ~11KB don't cap it), attacking the stall-fill problem
// with TLP -- the only axis that separated 80us from 186us. B re-reads are
// L2-resident (FETCH stays input-dominated). Per-wave code path, margins,
// two-pass candidate semantics, and exact f64 resolve are R0's, with s-sets
// 4->2 and 2-lanes-per-row staging the only edits.
// ---------------------------------------------------------------------------
__global__ __launch_bounds__(64, 2) void label_kernel(
        const float* __restrict__ inpt, const float* __restrict__ centers,
        const double* __restrict__ cnorm_d, const float* __restrict__ cnorm_f,
        const int* __restrict__ maxc_i, const unsigned short* __restrict__ cbf,
        int* __restrict__ out) {
    __shared__ unsigned short A_lds[TM][72];   // 144B rows: frag reads 2-way (free)
    __shared__ float cn_lds[NCENT];
    __shared__ float margin_lds[TM];
    __shared__ int   cand[TM][MAXC];
    __shared__ int   ccount[TM];

    const int lane = threadIdx.x;
    const int rowBase = blockIdx.x * TM;

    // ---- stage: 2 lanes per row, each a contiguous 128B half (coalesced)
    {
        const int row = lane >> 1, hf = lane & 1;
        const float* xp = inpt + (size_t)(rowBase + row) * INPT_DIM + COL_OFF + hf * 32;
        float nx2 = 0.f;
#pragma unroll
        for (int j = 0; j < 8; ++j) {
            float4 v = *reinterpret_cast<const float4*>(xp + j * 4);
            nx2 = fmaf(v.x, v.x, fmaf(v.y, v.y, fmaf(v.z, v.z, fmaf(v.w, v.w, nx2))));
            unsigned u0 = (unsigned)f2bf(v.x) | ((unsigned)f2bf(v.y) << 16);
            unsigned u1 = (unsigned)f2bf(v.z) | ((unsigned)f2bf(v.w) << 16);
            int col = hf * 32 + j * 4;
            *reinterpret_cast<unsigned*>(&A_lds[row][col])     = u0;
            *reinterpret_cast<unsigned*>(&A_lds[row][col + 2]) = u1;
        }
        // half-norm combine: lanes 2r, 2r+1 share the row
        nx2 += __shfl_xor(nx2, 1);
        // bf16 score err <= 2^-7|x||c| each way; formula unchanged since R3 (absmax=0)
        if (hf == 0)
            margin_lds[row] = (1.5f / 64.f) * sqrtf(nx2) * __int_as_float(maxc_i[0]) + 1e-3f;
        if (lane < TM) ccount[lane] = 0;
#pragma unroll
        for (int i = 0; i < 4; ++i) {
            int idx = i * 256 + lane * 4;
            *reinterpret_cast<float4*>(&cn_lds[idx]) =
                *reinterpret_cast<const float4*>(cnorm_f + idx);
        }
    }
    __syncthreads();

    const int m = lane & 15, q = lane >> 4;
    short8 af0[NS], af1[NS];   // m89: A[m=lane&15][k=q*8+j]; 2 sets of 16 rows
#pragma unroll
    for (int s = 0; s < NS; ++s) {
        af0[s] = *reinterpret_cast<const short8*>(&A_lds[s * 16 + m][q * 8]);
        af1[s] = *reinterpret_cast<const short8*>(&A_lds[s * 16 + m][32 + q * 8]);
    }

    const short8* bfrag = reinterpret_cast<const short8*>(cbf);

    auto loadGroup = [&](short8 (&B0)[4], short8 (&B1)[4], float (&CN)[4], int tb) {
#pragma unroll
        for (int j = 0; j < 4; ++j) {
            B0[j] = bfrag[((tb + j) * 2 + 0) * 64 + lane];
            B1[j] = bfrag[((tb + j) * 2 + 1) * 64 + lane];
            CN[j] = cn_lds[(tb + j) * 16 + m];
        }
    };

    // ================= pass 1: running min only =================
    float rmin[NS][4];
#pragma unroll
    for (int s = 0; s < NS; ++s)
#pragma unroll
        for (int r4 = 0; r4 < 4; ++r4) rmin[s][r4] = INFINITY;

    auto comp1 = [&](short8 (&B0)[4], short8 (&B1)[4], float (&CN)[4]) {
#pragma unroll
        for (int j = 0; j < 4; ++j) {
#pragma unroll
            for (int s = 0; s < NS; ++s) {
                f32x4 acc = {0.f, 0.f, 0.f, 0.f};
                acc = __builtin_amdgcn_mfma_f32_16x16x32_bf16(af0[s], B0[j], acc, 0, 0, 0);
                acc = __builtin_amdgcn_mfma_f32_16x16x32_bf16(af1[s], B1[j], acc, 0, 0, 0);
#pragma unroll
                for (int r4 = 0; r4 < 4; ++r4)   // D: col=m (center), row=q*4+r4
                    rmin[s][r4] = fminf(rmin[s][r4], fmaf(-2.f, acc[r4], CN[j]));
            }
        }
    };

    {
        short8 X0[4], X1[4], Y0[4], Y1[4];
        float  XC[4], YC[4];
        loadGroup(X0, X1, XC, 0);
        for (int gp = 0; gp < 8; ++gp) {          // dynamic loop: buffers stay regs
            int t0 = gp * 8;
            loadGroup(Y0, Y1, YC, t0 + 4);        // prefetch while computing X
            comp1(X0, X1, XC);
            if (gp < 7) loadGroup(X0, X1, XC, t0 + 8);
            comp1(Y0, Y1, YC);
        }
    }

    // ---- one cross-lane reduction (16-lane m-groups) -> per-row thresholds
    float thresh[NS][4], tmax[NS];
    float tmax_all = -INFINITY;
#pragma unroll
    for (int s = 0; s < NS; ++s) {
        tmax[s] = -INFINITY;
#pragma unroll
        for (int r4 = 0; r4 < 4; ++r4) {
            float v = rmin[s][r4];
            v = fminf(v, __shfl_xor(v, 1));
            v = fminf(v, __shfl_xor(v, 2));
            v = fminf(v, __shfl_xor(v, 4));
            v = fminf(v, __shfl_xor(v, 8));
            v += margin_lds[s * 16 + q * 4 + r4];
            thresh[s][r4] = v;
            tmax[s] = fmaxf(tmax[s], v);
        }
        tmax_all = fmaxf(tmax_all, tmax[s]);
    }

    // ================= pass 2: recompute + append candidates =================
    auto comp2 = [&](short8 (&B0)[4], short8 (&B1)[4], float (&CN)[4], int tb) {
#pragma unroll
        for (int j = 0; j < 4; ++j) {
            f32x4 sc[NS];
            float cmin = INFINITY;
#pragma unroll
            for (int s = 0; s < NS; ++s) {
                f32x4 acc = {0.f, 0.f, 0.f, 0.f};
                acc = __builtin_amdgcn_mfma_f32_16x16x32_bf16(af0[s], B0[j], acc, 0, 0, 0);
                acc = __builtin_amdgcn_mfma_f32_16x16x32_bf16(af1[s], B1[j], acc, 0, 0, 0);
#pragma unroll
                for (int r4 = 0; r4 < 4; ++r4) {
                    sc[s][r4] = fmaf(-2.f, acc[r4], CN[j]);
                    cmin = fminf(cmin, sc[s][r4]);
                }
            }
            if (cmin < tmax_all) {
#pragma unroll
                for (int s = 0; s < NS; ++s) {
                    float smin = fminf(fminf(sc[s][0], sc[s][1]), fminf(sc[s][2], sc[s][3]));
                    if (smin < tmax[s]) {
#pragma unroll
                        for (int r4 = 0; r4 < 4; ++r4) {
                            if (sc[s][r4] < thresh[s][r4]) {   // pass1==pass2 scores (determinism)
                                int row = s * 16 + q * 4 + r4;
                                int slot = atomicAdd(&ccount[row], 1);
                                if (slot < MAXC) cand[row][slot] = (tb + j) * 16 + m;
                            }
                        }
                    }
                }
            }
        }
    };

    {
        short8 X0[4], X1[4], Y0[4], Y1[4];
        float  XC[4], YC[4];
        loadGroup(X0, X1, XC, 0);
        for (int gp = 0; gp < 8; ++gp) {
            int t0 = gp * 8;
            loadGroup(Y0, Y1, YC, t0 + 4);
            comp2(X0, X1, XC, t0);
            if (gp < 7) loadGroup(X0, X1, XC, t0 + 8);
            comp2(Y0, Y1, YC, t0 + 4);
        }
    }
    __syncthreads();

    // ---- exact f64 resolve: lane r resolves row r (argmin guaranteed in list)
    if (lane < TM) {
        int cnt = ccount[lane];
        int best;
        if (cnt == 1) {
            best = cand[lane][0];
        } else {
            const float* xp = inpt + (size_t)(rowBase + lane) * INPT_DIM + COL_OFF;
            double bestv = 1e300;
            best = 0x7fffffff;
            if (cnt <= MAXC) {
                for (int j = 0; j < cnt; ++j) {
                    int k = cand[lane][j];
                    double s = exact_score(centers + (size_t)k * DIM, xp, cnorm_d[k]);
                    if (s < bestv || (s == bestv && k < best)) { bestv = s; best = k; }
                }
            } else {  // overflow fallback: full exact scan (P ~ 0)
                for (int k = 0; k < NCENT; ++k) {
                    double s = exact_score(centers + (size_t)k * DIM, xp, cnorm_d[k]);
                    if (s < bestv) { bestv = s; best = k; }
                }
            }
        }
        out[rowBase + lane] = best;
    }
}

// ---------------------------------------------------------------------------
extern "C" void kernel_launch(void* const* d_in, const int* in_sizes, int n_in,
                              void* d_out, int out_size, void* d_ws, size_t ws_size,
                              hipStream_t stream) {
    const float* inpt     = (const float*)d_in[0];
    const float* centers1 = (const float*)d_in[2];   // centers0 (d_in[1]) unused
    int* out = (int*)d_out;

    char* ws = (char*)d_ws;
    double* cnorm_d = (double*)ws;
    float*  cnorm_f = (float*)(ws + 8192);
    int*    maxc_i  = (int*)(ws + 12288);
    unsigned short* cbf = (unsigned short*)(ws + 16384);

    prep_kernel<<<16, 256, 0, stream>>>(centers1, cnorm_d, cnorm_f, maxc_i, cbf);
    label_kernel<<<N_ROWS / TM, 64, 0, stream>>>(inpt, centers1, cnorm_d, cnorm_f,
                                                 maxc_i, cbf, out);
}